// Round 8
// baseline (605.754 us; speedup 1.0000x reference)
//
#include <hip/hip_runtime.h>

#define HID 128
#define NG 64

__device__ __forceinline__ float lrelu(float v) { return v > 0.0f ? v : 0.2f * v; }

__device__ __forceinline__ unsigned int bf16rne(float f) {
    unsigned int u = __float_as_uint(f);
    return (u + 0x7fffu + ((u >> 16) & 1u)) >> 16;
}
__device__ __forceinline__ unsigned int packbf(float a, float b) {
    return bf16rne(a) | (bf16rne(b) << 16);
}

// ================= unified node-transform GEMM (h stored as bf16) =================
// BN=true: scale/shift computed in-block from bnsum (BN fold; removes k_bnscale)
template <int K, bool BN>
__global__ __launch_bounds__(256) void k_gemm(const float* __restrict__ xin,
        const float* __restrict__ W,
        const double* __restrict__ bnsum, const float* __restrict__ gamma, const float* __restrict__ beta,
        const float* __restrict__ attS, const float* __restrict__ attD,
        unsigned short* __restrict__ h, float* __restrict__ as_, float* __restrict__ ad_, int N)
{
    __shared__ float xs[64][K];
    __shared__ __align__(16) float sc_s[K];
    __shared__ __align__(16) float sh_s[K];
    constexpr int K4 = K / 4;
    int t = threadIdx.x;
    int cq = t & 31;
    int nr = t >> 5;

    if (BN) {
        if (t < K) {
            double mu = bnsum[t] / (double)N;
            double var = bnsum[K + t] / (double)N - mu * mu;
            if (var < 0.0) var = 0.0;
            double rs = 1.0 / sqrt(var + 1e-5);
            float sc = (float)((double)gamma[t] * rs);
            sc_s[t] = sc;
            sh_s[t] = beta[t] - (float)mu * sc;
        }
        __syncthreads();
    }

    float4 atS = ((const float4*)attS)[cq];
    float4 atD = ((const float4*)attD)[cq];

    for (int n0 = blockIdx.x * 64; n0 < N; n0 += gridDim.x * 64) {
        int nrem = N - n0; if (nrem > 64) nrem = 64;
        for (int idx = t; idx < 64 * K4; idx += 256) {
            int n = idx / K4, k4 = idx % K4;
            float4 v = make_float4(0.f, 0.f, 0.f, 0.f);
            if (n < nrem) {
                v = ((const float4*)(xin + (size_t)(n0 + n) * K))[k4];
                if (BN) {
                    float4 sc = ((const float4*)sc_s)[k4];
                    float4 sh = ((const float4*)sh_s)[k4];
                    v.x = fmaf(v.x, sc.x, sh.x); v.x = v.x > 0.f ? v.x : 0.f;
                    v.y = fmaf(v.y, sc.y, sh.y); v.y = v.y > 0.f ? v.y : 0.f;
                    v.z = fmaf(v.z, sc.z, sh.z); v.z = v.z > 0.f ? v.z : 0.f;
                    v.w = fmaf(v.w, sc.w, sh.w); v.w = v.w > 0.f ? v.w : 0.f;
                }
            }
            *(float4*)(&xs[n][k4 * 4]) = v;
        }
        __syncthreads();

        float4 acc[8];
#pragma unroll
        for (int j = 0; j < 8; ++j) acc[j] = make_float4(0.f, 0.f, 0.f, 0.f);

        const float4* W4 = (const float4*)W;
#pragma unroll 2
        for (int k4 = 0; k4 < K4; ++k4) {
            float4 w0 = W4[(k4 * 4 + 0) * 32 + cq];
            float4 w1 = W4[(k4 * 4 + 1) * 32 + cq];
            float4 w2 = W4[(k4 * 4 + 2) * 32 + cq];
            float4 w3 = W4[(k4 * 4 + 3) * 32 + cq];
#pragma unroll
            for (int j = 0; j < 8; ++j) {
                float4 xv = *(const float4*)(&xs[nr * 8 + j][k4 * 4]);
                acc[j].x = fmaf(xv.x, w0.x, acc[j].x);
                acc[j].y = fmaf(xv.x, w0.y, acc[j].y);
                acc[j].z = fmaf(xv.x, w0.z, acc[j].z);
                acc[j].w = fmaf(xv.x, w0.w, acc[j].w);
                acc[j].x = fmaf(xv.y, w1.x, acc[j].x);
                acc[j].y = fmaf(xv.y, w1.y, acc[j].y);
                acc[j].z = fmaf(xv.y, w1.z, acc[j].z);
                acc[j].w = fmaf(xv.y, w1.w, acc[j].w);
                acc[j].x = fmaf(xv.z, w2.x, acc[j].x);
                acc[j].y = fmaf(xv.z, w2.y, acc[j].y);
                acc[j].z = fmaf(xv.z, w2.z, acc[j].z);
                acc[j].w = fmaf(xv.z, w2.w, acc[j].w);
                acc[j].x = fmaf(xv.w, w3.x, acc[j].x);
                acc[j].y = fmaf(xv.w, w3.y, acc[j].y);
                acc[j].z = fmaf(xv.w, w3.z, acc[j].z);
                acc[j].w = fmaf(xv.w, w3.w, acc[j].w);
            }
        }

#pragma unroll
        for (int j = 0; j < 8; ++j) {
            int n = nr * 8 + j;
            bool ok = (n < nrem);
            if (ok) {
                unsigned int lo = packbf(acc[j].x, acc[j].y);
                unsigned int hi = packbf(acc[j].z, acc[j].w);
                ((uint2*)(h + (size_t)(n0 + n) * 128))[cq] = make_uint2(lo, hi);
            }
            float ps = acc[j].x * atS.x + acc[j].y * atS.y + acc[j].z * atS.z + acc[j].w * atS.w;
            float pd = acc[j].x * atD.x + acc[j].y * atD.y + acc[j].z * atD.z + acc[j].w * atD.w;
            ps += __shfl_xor(ps, 1); pd += __shfl_xor(pd, 1);
            ps += __shfl_xor(ps, 2); pd += __shfl_xor(pd, 2);
            ps += __shfl_xor(ps, 4); pd += __shfl_xor(pd, 4);
            if (ok && (cq & 7) == 0) {
                int hd = cq >> 3;
                as_[(size_t)(n0 + n) * 4 + hd] = ps;
                ad_[(size_t)(n0 + n) * 4 + hd] = pd;
            }
        }
        __syncthreads();
    }
}

// ================= CSR build: bucket radix (bucket = dst >> 8), packed 4B =================
__global__ __launch_bounds__(256) void k_bhist(const int* __restrict__ ei,
        int* __restrict__ bSize, int E, int nB)
{
    __shared__ int hist[1024];
    int t = threadIdx.x;
    for (int i = t; i < nB; i += 256) hist[i] = 0;
    __syncthreads();
    int chunk = (E + gridDim.x - 1) / gridDim.x;
    int lo = blockIdx.x * chunk, hi = lo + chunk; if (hi > E) hi = E;
    for (int e = lo + t; e < hi; e += 256) atomicAdd(&hist[ei[E + e] >> 8], 1);
    __syncthreads();
    for (int i = t; i < nB; i += 256) { int c = hist[i]; if (c) atomicAdd(&bSize[i], c); }
}

__global__ __launch_bounds__(512) void k_bscan(const int* __restrict__ bSize,
        int* __restrict__ bOff, int* __restrict__ bCur, int nB)
{
    __shared__ int part[512];
    int t = threadIdx.x;
    part[t] = (t < nB) ? bSize[t] : 0;
    __syncthreads();
    for (int off = 1; off < 512; off <<= 1) {
        int u = (t >= off) ? part[t - off] : 0;
        __syncthreads();
        part[t] += u;
        __syncthreads();
    }
    int ex = (t == 0) ? 0 : part[t - 1];
    if (t < nB) { bOff[t] = ex; bCur[t] = ex; }
    if (t == nB - 1) bOff[nB] = part[t];
}

__global__ __launch_bounds__(256) void k_part(const int* __restrict__ ei,
        int* __restrict__ bCur, unsigned int* __restrict__ bucketBuf, int E, int nB)
{
    __shared__ int hist[1024];
    __shared__ int base[1024];
    int t = threadIdx.x;
    int chunk = (E + gridDim.x - 1) / gridDim.x;
    int lo = blockIdx.x * chunk, hi = lo + chunk; if (hi > E) hi = E;
    for (int i = t; i < nB; i += 256) hist[i] = 0;
    __syncthreads();
    for (int e = lo + t; e < hi; e += 256) atomicAdd(&hist[ei[E + e] >> 8], 1);
    __syncthreads();
    for (int i = t; i < nB; i += 256) {
        int c = hist[i];
        base[i] = c ? atomicAdd(&bCur[i], c) : 0;
        hist[i] = 0;
    }
    __syncthreads();
    for (int e = lo + t; e < hi; e += 256) {
        int s = ei[e], d = ei[E + e];
        int b = d >> 8;
        int pos = base[b] + atomicAdd(&hist[b], 1);
        bucketBuf[pos] = ((unsigned)(d & 255) << 24) | (unsigned)s;  // N < 2^24
    }
}

__global__ __launch_bounds__(256) void k_build(const unsigned int* __restrict__ bucketBuf,
        const int* __restrict__ bOff, int* __restrict__ rowPtr, int* __restrict__ sSrc, int N)
{
    __shared__ int lhist[256];
    __shared__ int sOut[8192];
    int b = blockIdx.x;
    int dlo = b << 8;
    int dhi = dlo + 256; if (dhi > N) dhi = N;
    int base = bOff[b], end = bOff[b + 1];
    int sz = end - base;
    int t = threadIdx.x;
    lhist[t] = 0;
    __syncthreads();
    for (int i = t; i < sz; i += 256) {
        atomicAdd(&lhist[bucketBuf[base + i] >> 24], 1);
    }
    __syncthreads();
    for (int off = 1; off < 256; off <<= 1) {
        int u = (t >= off) ? lhist[t - off] : 0;
        __syncthreads();
        lhist[t] += u;
        __syncthreads();
    }
    int pfx = (t == 0) ? 0 : lhist[t - 1];
    if (dlo + t < dhi) rowPtr[dlo + t] = base + pfx;
    if (t == 0 && dhi == N) rowPtr[N] = end;
    __syncthreads();
    lhist[t] = pfx;
    __syncthreads();
    if (sz <= 8192) {
        for (int i = t; i < sz; i += 256) {
            unsigned int p = bucketBuf[base + i];
            int pos = atomicAdd(&lhist[p >> 24], 1);
            sOut[pos] = (int)(p & 0xffffffu);
        }
        __syncthreads();
        for (int i = t; i < sz; i += 256) sSrc[base + i] = sOut[i];
    } else {
        for (int i = t; i < sz; i += 256) {
            unsigned int p = bucketBuf[base + i];
            int pos = atomicAdd(&lhist[p >> 24], 1);
            sSrc[base + pos] = (int)(p & 0xffffffu);
        }
    }
}

// ================= fused softmax + CSR SpMM aggregation (LDS w-stash) =================
// 32 threads per dst. Pass 1: owning lane computes per-edge w (4 heads) ONCE,
// stashes in LDS (cap 64 edges/dst; fallback recompute beyond), shfl-reduces sums.
// Pass 2: unroll-8 gather of bf16 h rows; w via LDS broadcast; scale 1/sum.
__global__ __launch_bounds__(256) void k_agg(const int* __restrict__ rowPtr,
        const int* __restrict__ sSrc,
        const float* __restrict__ as_, const float* __restrict__ ad_,
        const unsigned short* __restrict__ h, float* __restrict__ out, int N)
{
    __shared__ float wst[8][64][4];
    int t = threadIdx.x;
    int lane = t & 31;
    int g = t >> 5;
    int d = blockIdx.x * 8 + g;
    bool valid = (d < N);
    int b0 = 0, deg = 0;
    float4 adv = make_float4(0.f, 0.f, 0.f, 0.f);
    if (valid) { b0 = rowPtr[d]; deg = rowPtr[d + 1] - b0; adv = ((const float4*)ad_)[d]; }

    float4 sm = make_float4(0.f, 0.f, 0.f, 0.f);
    for (int e = lane; e < deg; e += 32) {
        int s = sSrc[b0 + e];
        float4 a = ((const float4*)as_)[s];
        float4 w;
        w.x = __expf(lrelu(a.x + adv.x));
        w.y = __expf(lrelu(a.y + adv.y));
        w.z = __expf(lrelu(a.z + adv.z));
        w.w = __expf(lrelu(a.w + adv.w));
        if (e < 64) *(float4*)(&wst[g][e][0]) = w;
        sm.x += w.x; sm.y += w.y; sm.z += w.z; sm.w += w.w;
    }
#pragma unroll
    for (int off = 1; off < 32; off <<= 1) {
        sm.x += __shfl_xor(sm.x, off);
        sm.y += __shfl_xor(sm.y, off);
        sm.z += __shfl_xor(sm.z, off);
        sm.w += __shfl_xor(sm.w, off);
    }
    __syncthreads();

    int hd = lane >> 3;
    float sumh = (hd == 0) ? sm.x : (hd == 1) ? sm.y : (hd == 2) ? sm.z : sm.w;
    float advh = (hd == 0) ? adv.x : (hd == 1) ? adv.y : (hd == 2) ? adv.z : adv.w;
    float inv = 1.f / (sumh + 1e-16f);

    const uint2* h2 = (const uint2*)h;
    const int* sp = sSrc + b0;
    float4 acc = make_float4(0.f, 0.f, 0.f, 0.f);
    int dc = deg < 64 ? deg : 64;
    int j = 0;
#define AGG1(S, W) { uint2 u = h2[(size_t)(S) * 32 + lane]; \
        acc.x = fmaf((W), __uint_as_float(u.x << 16), acc.x); \
        acc.y = fmaf((W), __uint_as_float(u.x & 0xffff0000u), acc.y); \
        acc.z = fmaf((W), __uint_as_float(u.y << 16), acc.z); \
        acc.w = fmaf((W), __uint_as_float(u.y & 0xffff0000u), acc.w); }
    for (; j + 8 <= dc; j += 8) {
        int s0 = sp[j], s1 = sp[j+1], s2 = sp[j+2], s3 = sp[j+3];
        int s4 = sp[j+4], s5 = sp[j+5], s6 = sp[j+6], s7 = sp[j+7];
        float w0 = wst[g][j][hd],   w1 = wst[g][j+1][hd], w2 = wst[g][j+2][hd], w3 = wst[g][j+3][hd];
        float w4 = wst[g][j+4][hd], w5 = wst[g][j+5][hd], w6 = wst[g][j+6][hd], w7 = wst[g][j+7][hd];
        uint2 u0 = h2[(size_t)s0*32+lane], u1 = h2[(size_t)s1*32+lane];
        uint2 u2 = h2[(size_t)s2*32+lane], u3 = h2[(size_t)s3*32+lane];
        uint2 u4 = h2[(size_t)s4*32+lane], u5 = h2[(size_t)s5*32+lane];
        uint2 u6 = h2[(size_t)s6*32+lane], u7 = h2[(size_t)s7*32+lane];
        acc.x = fmaf(w0, __uint_as_float(u0.x << 16), acc.x);
        acc.y = fmaf(w0, __uint_as_float(u0.x & 0xffff0000u), acc.y);
        acc.z = fmaf(w0, __uint_as_float(u0.y << 16), acc.z);
        acc.w = fmaf(w0, __uint_as_float(u0.y & 0xffff0000u), acc.w);
        acc.x = fmaf(w1, __uint_as_float(u1.x << 16), acc.x);
        acc.y = fmaf(w1, __uint_as_float(u1.x & 0xffff0000u), acc.y);
        acc.z = fmaf(w1, __uint_as_float(u1.y << 16), acc.z);
        acc.w = fmaf(w1, __uint_as_float(u1.y & 0xffff0000u), acc.w);
        acc.x = fmaf(w2, __uint_as_float(u2.x << 16), acc.x);
        acc.y = fmaf(w2, __uint_as_float(u2.x & 0xffff0000u), acc.y);
        acc.z = fmaf(w2, __uint_as_float(u2.y << 16), acc.z);
        acc.w = fmaf(w2, __uint_as_float(u2.y & 0xffff0000u), acc.w);
        acc.x = fmaf(w3, __uint_as_float(u3.x << 16), acc.x);
        acc.y = fmaf(w3, __uint_as_float(u3.x & 0xffff0000u), acc.y);
        acc.z = fmaf(w3, __uint_as_float(u3.y << 16), acc.z);
        acc.w = fmaf(w3, __uint_as_float(u3.y & 0xffff0000u), acc.w);
        acc.x = fmaf(w4, __uint_as_float(u4.x << 16), acc.x);
        acc.y = fmaf(w4, __uint_as_float(u4.x & 0xffff0000u), acc.y);
        acc.z = fmaf(w4, __uint_as_float(u4.y << 16), acc.z);
        acc.w = fmaf(w4, __uint_as_float(u4.y & 0xffff0000u), acc.w);
        acc.x = fmaf(w5, __uint_as_float(u5.x << 16), acc.x);
        acc.y = fmaf(w5, __uint_as_float(u5.x & 0xffff0000u), acc.y);
        acc.z = fmaf(w5, __uint_as_float(u5.y << 16), acc.z);
        acc.w = fmaf(w5, __uint_as_float(u5.y & 0xffff0000u), acc.w);
        acc.x = fmaf(w6, __uint_as_float(u6.x << 16), acc.x);
        acc.y = fmaf(w6, __uint_as_float(u6.x & 0xffff0000u), acc.y);
        acc.z = fmaf(w6, __uint_as_float(u6.y << 16), acc.z);
        acc.w = fmaf(w6, __uint_as_float(u6.y & 0xffff0000u), acc.w);
        acc.x = fmaf(w7, __uint_as_float(u7.x << 16), acc.x);
        acc.y = fmaf(w7, __uint_as_float(u7.x & 0xffff0000u), acc.y);
        acc.z = fmaf(w7, __uint_as_float(u7.y << 16), acc.z);
        acc.w = fmaf(w7, __uint_as_float(u7.y & 0xffff0000u), acc.w);
    }
    for (; j < dc; ++j) {
        float w = wst[g][j][hd];
        AGG1(sp[j], w);
    }
    for (; j < deg; ++j) {  // deg > 64 fallback (practically never)
        int s = sp[j];
        float w = __expf(lrelu(as_[(size_t)s * 4 + hd] + advh));
        AGG1(s, w);
    }
#undef AGG1
    if (valid) {
        acc.x *= inv; acc.y *= inv; acc.z *= inv; acc.w *= inv;
        ((float4*)out)[(size_t)d * 32 + lane] = acc;
    }
}

// ================= BN stats (float4 lanes, LDS tree, f64 atomics) =================
__global__ __launch_bounds__(256) void k_bnstats(const float* __restrict__ x,
        double* __restrict__ sums, int N)
{
    __shared__ float4 r1[256], r2[256];
    int t = threadIdx.x;
    int lane = t & 31;
    int rg = t >> 5;
    const float4* x4 = (const float4*)x;
    float4 s1 = make_float4(0.f, 0.f, 0.f, 0.f);
    float4 s2 = make_float4(0.f, 0.f, 0.f, 0.f);
    for (int n = blockIdx.x * 8 + rg; n < N; n += gridDim.x * 8) {
        float4 v = x4[(size_t)n * 32 + lane];
        s1.x += v.x; s1.y += v.y; s1.z += v.z; s1.w += v.w;
        s2.x += v.x * v.x; s2.y += v.y * v.y; s2.z += v.z * v.z; s2.w += v.w * v.w;
    }
    r1[t] = s1; r2[t] = s2;
    __syncthreads();
    if (t < 32) {
        float4 a = r1[t], b = r2[t];
        for (int k = 1; k < 8; ++k) {
            float4 c = r1[t + 32 * k], e = r2[t + 32 * k];
            a.x += c.x; a.y += c.y; a.z += c.z; a.w += c.w;
            b.x += e.x; b.y += e.y; b.z += e.z; b.w += e.w;
        }
        atomicAdd(&sums[t * 4 + 0], (double)a.x);
        atomicAdd(&sums[t * 4 + 1], (double)a.y);
        atomicAdd(&sums[t * 4 + 2], (double)a.z);
        atomicAdd(&sums[t * 4 + 3], (double)a.w);
        atomicAdd(&sums[128 + t * 4 + 0], (double)b.x);
        atomicAdd(&sums[128 + t * 4 + 1], (double)b.y);
        atomicAdd(&sums[128 + t * 4 + 2], (double)b.z);
        atomicAdd(&sums[128 + t * 4 + 3], (double)b.w);
    }
}

// ================= pool (BN fold in prologue; removes k_bnscale2) =================
__global__ __launch_bounds__(128) void k_pool(const float* __restrict__ x,
        const int* __restrict__ batch,
        const double* __restrict__ bnsum, const float* __restrict__ gamma, const float* __restrict__ beta,
        float* __restrict__ gsum, float* __restrict__ gcnt, int N)
{
    __shared__ __align__(16) float sc_s[128];
    __shared__ __align__(16) float sh_s[128];
    int t = threadIdx.x;
    {
        double mu = bnsum[t] / (double)N;
        double var = bnsum[128 + t] / (double)N - mu * mu;
        if (var < 0.0) var = 0.0;
        double rs = 1.0 / sqrt(var + 1e-5);
        float sc = (float)((double)gamma[t] * rs);
        sc_s[t] = sc;
        sh_s[t] = beta[t] - (float)mu * sc;
    }
    __syncthreads();

    int lane = t & 31;
    int r = t >> 5;
    int n0 = blockIdx.x * 64;
    if (n0 >= N) return;
    int n1 = n0 + 64; if (n1 > N) n1 = N;
    float4 sc = ((const float4*)sc_s)[lane];
    float4 sh = ((const float4*)sh_s)[lane];
    float4 acc = make_float4(0.f, 0.f, 0.f, 0.f);
    int cnt = 0, cur = -1;
    for (int n = n0 + r; n < n1; n += 4) {
        int g = batch[n];
        if (g != cur) {
            if (cur >= 0) {
                atomicAdd(&gsum[cur * 128 + lane * 4 + 0], acc.x);
                atomicAdd(&gsum[cur * 128 + lane * 4 + 1], acc.y);
                atomicAdd(&gsum[cur * 128 + lane * 4 + 2], acc.z);
                atomicAdd(&gsum[cur * 128 + lane * 4 + 3], acc.w);
                if (lane == 0) atomicAdd(&gcnt[cur], (float)cnt);
            }
            acc = make_float4(0.f, 0.f, 0.f, 0.f); cnt = 0; cur = g;
        }
        float4 v = ((const float4*)x)[(size_t)n * 32 + lane];
        v.x = fmaf(v.x, sc.x, sh.x); v.x = v.x > 0.f ? v.x : 0.f;
        v.y = fmaf(v.y, sc.y, sh.y); v.y = v.y > 0.f ? v.y : 0.f;
        v.z = fmaf(v.z, sc.z, sh.z); v.z = v.z > 0.f ? v.z : 0.f;
        v.w = fmaf(v.w, sc.w, sh.w); v.w = v.w > 0.f ? v.w : 0.f;
        acc.x += v.x; acc.y += v.y; acc.z += v.z; acc.w += v.w;
        cnt++;
    }
    if (cur >= 0) {
        atomicAdd(&gsum[cur * 128 + lane * 4 + 0], acc.x);
        atomicAdd(&gsum[cur * 128 + lane * 4 + 1], acc.y);
        atomicAdd(&gsum[cur * 128 + lane * 4 + 2], acc.z);
        atomicAdd(&gsum[cur * 128 + lane * 4 + 3], acc.w);
        if (lane == 0) atomicAdd(&gcnt[cur], (float)cnt);
    }
}

// ================= dense head =================
__global__ __launch_bounds__(256) void k_head(const float* __restrict__ gsum, const float* __restrict__ gcnt,
        const float* __restrict__ d1W, const float* __restrict__ d1b,
        const float* __restrict__ g_d1, const float* __restrict__ b_d1,
        const float* __restrict__ d2W, const float* __restrict__ d2b,
        const float* __restrict__ g_d2, const float* __restrict__ b_d2,
        const float* __restrict__ fcW, const float* __restrict__ fcb,
        float* __restrict__ out)
{
    __shared__ float G[64 * 128];
    __shared__ float Y1[64 * 64];
    __shared__ float Y2[64 * 32];
    int t = threadIdx.x;
    for (int i = t; i < 64 * 128; i += 256) {
        int g = i >> 7;
        float cv = gcnt[g]; if (cv < 1.f) cv = 1.f;
        G[i] = gsum[i] / cv;
    }
    __syncthreads();
    for (int i = t; i < 64 * 64; i += 256) {
        int r = i >> 6, j = i & 63;
        float a = 0.f;
        for (int k = 0; k < 128; ++k) a = fmaf(G[r * 128 + k], d1W[k * 64 + j], a);
        Y1[i] = a + d1b[j];
    }
    __syncthreads();
    if (t < 64) {
        float s1 = 0.f, s2 = 0.f;
        for (int r = 0; r < 64; ++r) { float v = Y1[r * 64 + t]; s1 += v; s2 += v * v; }
        float mu = s1 / 64.f, var = s2 / 64.f - mu * mu; if (var < 0.f) var = 0.f;
        float rs = 1.0f / sqrtf(var + 1e-5f);
        float scv = g_d1[t] * rs, shv = b_d1[t] - mu * scv;
        for (int r = 0; r < 64; ++r) {
            float v = fmaf(Y1[r * 64 + t], scv, shv);
            Y1[r * 64 + t] = v > 0.f ? v : 0.f;
        }
    }
    __syncthreads();
    for (int i = t; i < 64 * 32; i += 256) {
        int r = i >> 5, j = i & 31;
        float a = 0.f;
        for (int k = 0; k < 64; ++k) a = fmaf(Y1[r * 64 + k], d2W[k * 32 + j], a);
        Y2[i] = a + d2b[j];
    }
    __syncthreads();
    if (t < 32) {
        float s1 = 0.f, s2 = 0.f;
        for (int r = 0; r < 64; ++r) { float v = Y2[r * 32 + t]; s1 += v; s2 += v * v; }
        float mu = s1 / 64.f, var = s2 / 64.f - mu * mu; if (var < 0.f) var = 0.f;
        float rs = 1.0f / sqrtf(var + 1e-5f);
        float scv = g_d2[t] * rs, shv = b_d2[t] - mu * scv;
        for (int r = 0; r < 64; ++r) {
            float v = fmaf(Y2[r * 32 + t], scv, shv);
            Y2[r * 32 + t] = v > 0.f ? v : 0.f;
        }
    }
    __syncthreads();
    {
        int r = t >> 2, j = t & 3;
        float a = 0.f;
        for (int k = 0; k < 32; ++k) a = fmaf(Y2[r * 32 + k], fcW[k * 4 + j], a);
        out[t] = a + fcb[j];
    }
}

extern "C" void kernel_launch(void* const* d_in, const int* in_sizes, int n_in,
                              void* d_out, int out_size, void* d_ws, size_t ws_size,
                              hipStream_t stream) {
    const int N = in_sizes[0] / 16;
    const int E = in_sizes[1] / 2;
    const int nB = (N + 255) >> 8;

    const float* x        = (const float*)d_in[0];
    const int*   ei       = (const int*)d_in[1];
    const int*   batch    = (const int*)d_in[2];
    const float* W1       = (const float*)d_in[3];
    const float* att_s1   = (const float*)d_in[5];
    const float* att_d1   = (const float*)d_in[6];
    const float* bn_g1    = (const float*)d_in[7];
    const float* bn_b1    = (const float*)d_in[8];
    const float* W2       = (const float*)d_in[9];
    const float* att_s2   = (const float*)d_in[11];
    const float* att_d2   = (const float*)d_in[12];
    const float* bn_g2    = (const float*)d_in[13];
    const float* bn_b2    = (const float*)d_in[14];
    const float* d1W      = (const float*)d_in[15];
    const float* d1b      = (const float*)d_in[16];
    const float* g_d1     = (const float*)d_in[17];
    const float* b_d1     = (const float*)d_in[18];
    const float* d2W      = (const float*)d_in[19];
    const float* d2b      = (const float*)d_in[20];
    const float* g_d2     = (const float*)d_in[21];
    const float* b_d2     = (const float*)d_in[22];
    const float* fcW      = (const float*)d_in[23];
    const float* fcb      = (const float*)d_in[24];
    float* out = (float*)d_out;

    float* ws = (float*)d_ws;
    size_t o = 0;
    unsigned short* hbuf = (unsigned short*)(ws + o); o += (size_t)N * 64;  // N*128 bf16
    float* outb   = ws + o;  o += (size_t)N * 128;
    float* as_    = ws + o;  o += (size_t)N * 4;
    float* ad_    = ws + o;  o += (size_t)N * 4;
    // ---- zero region (one memset): bnsumA, bnsumB, gsum, gcnt, bSize ----
    size_t zoff = o;
    double* bnsumA = (double*)(ws + o); o += 512;
    double* bnsumB = (double*)(ws + o); o += 512;
    float* gsum   = ws + o;  o += 64 * 128;
    float* gcnt   = ws + o;  o += 64;
    int*   bSize  = (int*)(ws + o); o += 1024;
    size_t zbytes = (o - zoff) * 4;
    int* rowPtr   = (int*)(ws + o); o += (size_t)N + 1;
    int* sSrc     = (int*)(ws + o); o += E;
    int* bOff     = (int*)(ws + o); o += 1025;
    int* bCur     = (int*)(ws + o); o += 1024;
    unsigned int* bucketBuf = (unsigned int*)(ws + o); o += E;

    hipMemsetAsync(ws + zoff, 0, zbytes, stream);

    // ---- CSR build (bucket radix, shared by both layers) ----
    k_bhist<<<256, 256, 0, stream>>>(ei, bSize, E, nB);
    k_bscan<<<1, 512, 0, stream>>>(bSize, bOff, bCur, nB);
    k_part<<<256, 256, 0, stream>>>(ei, bCur, bucketBuf, E, nB);
    k_build<<<nB, 256, 0, stream>>>(bucketBuf, bOff, rowPtr, sSrc, N);

    int gemm_grid = (N + 63) / 64;
    int agg_grid = (N + 7) / 8;

    // ---- layer 1 ----
    k_gemm<16, false><<<gemm_grid, 256, 0, stream>>>(x, W1, nullptr, nullptr, nullptr,
            att_s1, att_d1, hbuf, as_, ad_, N);
    k_agg<<<agg_grid, 256, 0, stream>>>(rowPtr, sSrc, as_, ad_, hbuf, outb, N);
    k_bnstats<<<512, 256, 0, stream>>>(outb, bnsumA, N);

    // ---- layer 2 (BN1 folded into gemm prologue) ----
    k_gemm<128, true><<<gemm_grid, 256, 0, stream>>>(outb, W2, bnsumA, bn_g1, bn_b1,
            att_s2, att_d2, hbuf, as_, ad_, N);
    k_agg<<<agg_grid, 256, 0, stream>>>(rowPtr, sSrc, as_, ad_, hbuf, outb, N);
    k_bnstats<<<512, 256, 0, stream>>>(outb, bnsumB, N);

    // ---- pool (BN2 folded) + head ----
    k_pool<<<(N + 63) / 64, 128, 0, stream>>>(outb, batch, bnsumB, bn_g2, bn_b2, gsum, gcnt, N);
    k_head<<<1, 256, 0, stream>>>(gsum, gcnt, d1W, d1b, g_d1, b_d1,
                                  d2W, d2b, g_d2, b_d2, fcW, fcb, out);
}

// Round 9
// 574.119 us; speedup vs baseline: 1.0551x; 1.0551x over previous
//
#include <hip/hip_runtime.h>

#define HID 128
#define NG 64

__device__ __forceinline__ float lrelu(float v) { return v > 0.0f ? v : 0.2f * v; }

__device__ __forceinline__ unsigned int bf16rne(float f) {
    unsigned int u = __float_as_uint(f);
    return (u + 0x7fffu + ((u >> 16) & 1u)) >> 16;
}
__device__ __forceinline__ unsigned int packbf(float a, float b) {
    return bf16rne(a) | (bf16rne(b) << 16);
}

// ================= unified node-transform GEMM (h stored as bf16) =================
// BN=true: scale/shift computed in-block from bnsum (BN fold)
template <int K, bool BN>
__global__ __launch_bounds__(256) void k_gemm(const float* __restrict__ xin,
        const float* __restrict__ W,
        const double* __restrict__ bnsum, const float* __restrict__ gamma, const float* __restrict__ beta,
        const float* __restrict__ attS, const float* __restrict__ attD,
        unsigned short* __restrict__ h, float* __restrict__ as_, float* __restrict__ ad_, int N)
{
    __shared__ float xs[64][K];
    __shared__ __align__(16) float sc_s[K];
    __shared__ __align__(16) float sh_s[K];
    constexpr int K4 = K / 4;
    int t = threadIdx.x;
    int cq = t & 31;
    int nr = t >> 5;

    if (BN) {
        if (t < K) {
            double mu = bnsum[t] / (double)N;
            double var = bnsum[K + t] / (double)N - mu * mu;
            if (var < 0.0) var = 0.0;
            double rs = 1.0 / sqrt(var + 1e-5);
            float sc = (float)((double)gamma[t] * rs);
            sc_s[t] = sc;
            sh_s[t] = beta[t] - (float)mu * sc;
        }
        __syncthreads();
    }

    float4 atS = ((const float4*)attS)[cq];
    float4 atD = ((const float4*)attD)[cq];

    for (int n0 = blockIdx.x * 64; n0 < N; n0 += gridDim.x * 64) {
        int nrem = N - n0; if (nrem > 64) nrem = 64;
        for (int idx = t; idx < 64 * K4; idx += 256) {
            int n = idx / K4, k4 = idx % K4;
            float4 v = make_float4(0.f, 0.f, 0.f, 0.f);
            if (n < nrem) {
                v = ((const float4*)(xin + (size_t)(n0 + n) * K))[k4];
                if (BN) {
                    float4 sc = ((const float4*)sc_s)[k4];
                    float4 sh = ((const float4*)sh_s)[k4];
                    v.x = fmaf(v.x, sc.x, sh.x); v.x = v.x > 0.f ? v.x : 0.f;
                    v.y = fmaf(v.y, sc.y, sh.y); v.y = v.y > 0.f ? v.y : 0.f;
                    v.z = fmaf(v.z, sc.z, sh.z); v.z = v.z > 0.f ? v.z : 0.f;
                    v.w = fmaf(v.w, sc.w, sh.w); v.w = v.w > 0.f ? v.w : 0.f;
                }
            }
            *(float4*)(&xs[n][k4 * 4]) = v;
        }
        __syncthreads();

        float4 acc[8];
#pragma unroll
        for (int j = 0; j < 8; ++j) acc[j] = make_float4(0.f, 0.f, 0.f, 0.f);

        const float4* W4 = (const float4*)W;
#pragma unroll 2
        for (int k4 = 0; k4 < K4; ++k4) {
            float4 w0 = W4[(k4 * 4 + 0) * 32 + cq];
            float4 w1 = W4[(k4 * 4 + 1) * 32 + cq];
            float4 w2 = W4[(k4 * 4 + 2) * 32 + cq];
            float4 w3 = W4[(k4 * 4 + 3) * 32 + cq];
#pragma unroll
            for (int j = 0; j < 8; ++j) {
                float4 xv = *(const float4*)(&xs[nr * 8 + j][k4 * 4]);
                acc[j].x = fmaf(xv.x, w0.x, acc[j].x);
                acc[j].y = fmaf(xv.x, w0.y, acc[j].y);
                acc[j].z = fmaf(xv.x, w0.z, acc[j].z);
                acc[j].w = fmaf(xv.x, w0.w, acc[j].w);
                acc[j].x = fmaf(xv.y, w1.x, acc[j].x);
                acc[j].y = fmaf(xv.y, w1.y, acc[j].y);
                acc[j].z = fmaf(xv.y, w1.z, acc[j].z);
                acc[j].w = fmaf(xv.y, w1.w, acc[j].w);
                acc[j].x = fmaf(xv.z, w2.x, acc[j].x);
                acc[j].y = fmaf(xv.z, w2.y, acc[j].y);
                acc[j].z = fmaf(xv.z, w2.z, acc[j].z);
                acc[j].w = fmaf(xv.z, w2.w, acc[j].w);
                acc[j].x = fmaf(xv.w, w3.x, acc[j].x);
                acc[j].y = fmaf(xv.w, w3.y, acc[j].y);
                acc[j].z = fmaf(xv.w, w3.z, acc[j].z);
                acc[j].w = fmaf(xv.w, w3.w, acc[j].w);
            }
        }

#pragma unroll
        for (int j = 0; j < 8; ++j) {
            int n = nr * 8 + j;
            bool ok = (n < nrem);
            if (ok) {
                unsigned int lo = packbf(acc[j].x, acc[j].y);
                unsigned int hi = packbf(acc[j].z, acc[j].w);
                ((uint2*)(h + (size_t)(n0 + n) * 128))[cq] = make_uint2(lo, hi);
            }
            float ps = acc[j].x * atS.x + acc[j].y * atS.y + acc[j].z * atS.z + acc[j].w * atS.w;
            float pd = acc[j].x * atD.x + acc[j].y * atD.y + acc[j].z * atD.z + acc[j].w * atD.w;
            ps += __shfl_xor(ps, 1); pd += __shfl_xor(pd, 1);
            ps += __shfl_xor(ps, 2); pd += __shfl_xor(pd, 2);
            ps += __shfl_xor(ps, 4); pd += __shfl_xor(pd, 4);
            if (ok && (cq & 7) == 0) {
                int hd = cq >> 3;
                as_[(size_t)(n0 + n) * 4 + hd] = ps;
                ad_[(size_t)(n0 + n) * 4 + hd] = pd;
            }
        }
        __syncthreads();
    }
}

// ================= CSR build: bucket radix (bucket = dst >> 8), packed 4B =================
__global__ __launch_bounds__(256) void k_bhist(const int* __restrict__ ei,
        int* __restrict__ bSize, int E, int nB)
{
    __shared__ int hist[1024];
    int t = threadIdx.x;
    for (int i = t; i < nB; i += 256) hist[i] = 0;
    __syncthreads();
    int chunk = (E + gridDim.x - 1) / gridDim.x;
    int lo = blockIdx.x * chunk, hi = lo + chunk; if (hi > E) hi = E;
    for (int e = lo + t; e < hi; e += 256) atomicAdd(&hist[ei[E + e] >> 8], 1);
    __syncthreads();
    for (int i = t; i < nB; i += 256) { int c = hist[i]; if (c) atomicAdd(&bSize[i], c); }
}

__global__ __launch_bounds__(512) void k_bscan(const int* __restrict__ bSize,
        int* __restrict__ bOff, int* __restrict__ bCur, int nB)
{
    __shared__ int part[512];
    int t = threadIdx.x;
    part[t] = (t < nB) ? bSize[t] : 0;
    __syncthreads();
    for (int off = 1; off < 512; off <<= 1) {
        int u = (t >= off) ? part[t - off] : 0;
        __syncthreads();
        part[t] += u;
        __syncthreads();
    }
    int ex = (t == 0) ? 0 : part[t - 1];
    if (t < nB) { bOff[t] = ex; bCur[t] = ex; }
    if (t == nB - 1) bOff[nB] = part[t];
}

__global__ __launch_bounds__(256) void k_part(const int* __restrict__ ei,
        int* __restrict__ bCur, unsigned int* __restrict__ bucketBuf, int E, int nB)
{
    __shared__ int hist[1024];
    __shared__ int base[1024];
    int t = threadIdx.x;
    int chunk = (E + gridDim.x - 1) / gridDim.x;
    int lo = blockIdx.x * chunk, hi = lo + chunk; if (hi > E) hi = E;
    for (int i = t; i < nB; i += 256) hist[i] = 0;
    __syncthreads();
    for (int e = lo + t; e < hi; e += 256) atomicAdd(&hist[ei[E + e] >> 8], 1);
    __syncthreads();
    for (int i = t; i < nB; i += 256) {
        int c = hist[i];
        base[i] = c ? atomicAdd(&bCur[i], c) : 0;
        hist[i] = 0;
    }
    __syncthreads();
    for (int e = lo + t; e < hi; e += 256) {
        int s = ei[e], d = ei[E + e];
        int b = d >> 8;
        int pos = base[b] + atomicAdd(&hist[b], 1);
        bucketBuf[pos] = ((unsigned)(d & 255) << 24) | (unsigned)s;  // N < 2^24
    }
}

__global__ __launch_bounds__(256) void k_build(const unsigned int* __restrict__ bucketBuf,
        const int* __restrict__ bOff, int* __restrict__ rowPtr, int* __restrict__ sSrc, int N)
{
    __shared__ int lhist[256];
    __shared__ int sOut[8192];
    int b = blockIdx.x;
    int dlo = b << 8;
    int dhi = dlo + 256; if (dhi > N) dhi = N;
    int base = bOff[b], end = bOff[b + 1];
    int sz = end - base;
    int t = threadIdx.x;
    lhist[t] = 0;
    __syncthreads();
    for (int i = t; i < sz; i += 256) {
        atomicAdd(&lhist[bucketBuf[base + i] >> 24], 1);
    }
    __syncthreads();
    for (int off = 1; off < 256; off <<= 1) {
        int u = (t >= off) ? lhist[t - off] : 0;
        __syncthreads();
        lhist[t] += u;
        __syncthreads();
    }
    int pfx = (t == 0) ? 0 : lhist[t - 1];
    if (dlo + t < dhi) rowPtr[dlo + t] = base + pfx;
    if (t == 0 && dhi == N) rowPtr[N] = end;
    __syncthreads();
    lhist[t] = pfx;
    __syncthreads();
    if (sz <= 8192) {
        for (int i = t; i < sz; i += 256) {
            unsigned int p = bucketBuf[base + i];
            int pos = atomicAdd(&lhist[p >> 24], 1);
            sOut[pos] = (int)(p & 0xffffffu);
        }
        __syncthreads();
        for (int i = t; i < sz; i += 256) sSrc[base + i] = sOut[i];
    } else {
        for (int i = t; i < sz; i += 256) {
            unsigned int p = bucketBuf[base + i];
            int pos = atomicAdd(&lhist[p >> 24], 1);
            sSrc[base + pos] = (int)(p & 0xffffffu);
        }
    }
}

// ================= fused softmax + CSR SpMM aggregation (16 lanes/dst) =================
// 16 lanes per dst: each lane owns 8 channels (uint4 = 16B of bf16 row).
// Pass 1: per-head exp sums (lanes stride 16 over edges, reduce over 16 lanes).
// Pass 2: each lane recomputes w for its head (4 lanes/head), gathers uint4.
// No LDS, no barriers -> occupancy-friendly; 4 dsts per wave for latency ILP.
__global__ __launch_bounds__(256) void k_agg(const int* __restrict__ rowPtr,
        const int* __restrict__ sSrc,
        const float* __restrict__ as_, const float* __restrict__ ad_,
        const unsigned short* __restrict__ h, float* __restrict__ out, int N)
{
    int t = threadIdx.x;
    int l = t & 15;
    int d = blockIdx.x * 16 + (t >> 4);
    if (d >= N) return;
    int hd = l >> 2;
    int b0 = rowPtr[d], b1 = rowPtr[d + 1];
    float4 adv = ((const float4*)ad_)[d];

    // pass 1: per-head sums of exp(lrelu(as+ad))
    float4 sm = make_float4(0.f, 0.f, 0.f, 0.f);
    for (int j = b0 + l; j < b1; j += 16) {
        int s = sSrc[j];
        float4 a = ((const float4*)as_)[s];
        sm.x += __expf(lrelu(a.x + adv.x));
        sm.y += __expf(lrelu(a.y + adv.y));
        sm.z += __expf(lrelu(a.z + adv.z));
        sm.w += __expf(lrelu(a.w + adv.w));
    }
#pragma unroll
    for (int off = 1; off < 16; off <<= 1) {
        sm.x += __shfl_xor(sm.x, off);
        sm.y += __shfl_xor(sm.y, off);
        sm.z += __shfl_xor(sm.z, off);
        sm.w += __shfl_xor(sm.w, off);
    }
    float sumh = (hd == 0) ? sm.x : (hd == 1) ? sm.y : (hd == 2) ? sm.z : sm.w;
    float advh = (hd == 0) ? adv.x : (hd == 1) ? adv.y : (hd == 2) ? adv.z : adv.w;
    float inv = 1.f / (sumh + 1e-16f);

    const uint4* h4 = (const uint4*)h;   // row = 16 x uint4
    float4 acc0 = make_float4(0.f, 0.f, 0.f, 0.f);
    float4 acc1 = make_float4(0.f, 0.f, 0.f, 0.f);
#define AGG1(S, W) { uint4 u = h4[(size_t)(S) * 16 + l]; \
        acc0.x = fmaf((W), __uint_as_float(u.x << 16), acc0.x); \
        acc0.y = fmaf((W), __uint_as_float(u.x & 0xffff0000u), acc0.y); \
        acc0.z = fmaf((W), __uint_as_float(u.y << 16), acc0.z); \
        acc0.w = fmaf((W), __uint_as_float(u.y & 0xffff0000u), acc0.w); \
        acc1.x = fmaf((W), __uint_as_float(u.z << 16), acc1.x); \
        acc1.y = fmaf((W), __uint_as_float(u.z & 0xffff0000u), acc1.y); \
        acc1.z = fmaf((W), __uint_as_float(u.w << 16), acc1.z); \
        acc1.w = fmaf((W), __uint_as_float(u.w & 0xffff0000u), acc1.w); }
    int j = b0;
    for (; j + 4 <= b1; j += 4) {
        int s0 = sSrc[j], s1 = sSrc[j + 1], s2 = sSrc[j + 2], s3 = sSrc[j + 3];
        float w0 = __expf(lrelu(as_[(size_t)s0 * 4 + hd] + advh));
        float w1 = __expf(lrelu(as_[(size_t)s1 * 4 + hd] + advh));
        float w2 = __expf(lrelu(as_[(size_t)s2 * 4 + hd] + advh));
        float w3 = __expf(lrelu(as_[(size_t)s3 * 4 + hd] + advh));
        uint4 u0 = h4[(size_t)s0 * 16 + l];
        uint4 u1 = h4[(size_t)s1 * 16 + l];
        uint4 u2 = h4[(size_t)s2 * 16 + l];
        uint4 u3 = h4[(size_t)s3 * 16 + l];
        acc0.x = fmaf(w0, __uint_as_float(u0.x << 16), acc0.x);
        acc0.y = fmaf(w0, __uint_as_float(u0.x & 0xffff0000u), acc0.y);
        acc0.z = fmaf(w0, __uint_as_float(u0.y << 16), acc0.z);
        acc0.w = fmaf(w0, __uint_as_float(u0.y & 0xffff0000u), acc0.w);
        acc1.x = fmaf(w0, __uint_as_float(u0.z << 16), acc1.x);
        acc1.y = fmaf(w0, __uint_as_float(u0.z & 0xffff0000u), acc1.y);
        acc1.z = fmaf(w0, __uint_as_float(u0.w << 16), acc1.z);
        acc1.w = fmaf(w0, __uint_as_float(u0.w & 0xffff0000u), acc1.w);
        acc0.x = fmaf(w1, __uint_as_float(u1.x << 16), acc0.x);
        acc0.y = fmaf(w1, __uint_as_float(u1.x & 0xffff0000u), acc0.y);
        acc0.z = fmaf(w1, __uint_as_float(u1.y << 16), acc0.z);
        acc0.w = fmaf(w1, __uint_as_float(u1.y & 0xffff0000u), acc0.w);
        acc1.x = fmaf(w1, __uint_as_float(u1.z << 16), acc1.x);
        acc1.y = fmaf(w1, __uint_as_float(u1.z & 0xffff0000u), acc1.y);
        acc1.z = fmaf(w1, __uint_as_float(u1.w << 16), acc1.z);
        acc1.w = fmaf(w1, __uint_as_float(u1.w & 0xffff0000u), acc1.w);
        acc0.x = fmaf(w2, __uint_as_float(u2.x << 16), acc0.x);
        acc0.y = fmaf(w2, __uint_as_float(u2.x & 0xffff0000u), acc0.y);
        acc0.z = fmaf(w2, __uint_as_float(u2.y << 16), acc0.z);
        acc0.w = fmaf(w2, __uint_as_float(u2.y & 0xffff0000u), acc0.w);
        acc1.x = fmaf(w2, __uint_as_float(u2.z << 16), acc1.x);
        acc1.y = fmaf(w2, __uint_as_float(u2.z & 0xffff0000u), acc1.y);
        acc1.z = fmaf(w2, __uint_as_float(u2.w << 16), acc1.z);
        acc1.w = fmaf(w2, __uint_as_float(u2.w & 0xffff0000u), acc1.w);
        acc0.x = fmaf(w3, __uint_as_float(u3.x << 16), acc0.x);
        acc0.y = fmaf(w3, __uint_as_float(u3.x & 0xffff0000u), acc0.y);
        acc0.z = fmaf(w3, __uint_as_float(u3.y << 16), acc0.z);
        acc0.w = fmaf(w3, __uint_as_float(u3.y & 0xffff0000u), acc0.w);
        acc1.x = fmaf(w3, __uint_as_float(u3.z << 16), acc1.x);
        acc1.y = fmaf(w3, __uint_as_float(u3.z & 0xffff0000u), acc1.y);
        acc1.z = fmaf(w3, __uint_as_float(u3.w << 16), acc1.z);
        acc1.w = fmaf(w3, __uint_as_float(u3.w & 0xffff0000u), acc1.w);
    }
    for (; j < b1; ++j) {
        int s = sSrc[j];
        float w = __expf(lrelu(as_[(size_t)s * 4 + hd] + advh));
        AGG1(s, w);
    }
#undef AGG1
    acc0.x *= inv; acc0.y *= inv; acc0.z *= inv; acc0.w *= inv;
    acc1.x *= inv; acc1.y *= inv; acc1.z *= inv; acc1.w *= inv;
    ((float4*)out)[(size_t)d * 32 + l * 2] = acc0;
    ((float4*)out)[(size_t)d * 32 + l * 2 + 1] = acc1;
}

// ================= BN stats (float4 lanes, LDS tree, f64 atomics) =================
__global__ __launch_bounds__(256) void k_bnstats(const float* __restrict__ x,
        double* __restrict__ sums, int N)
{
    __shared__ float4 r1[256], r2[256];
    int t = threadIdx.x;
    int lane = t & 31;
    int rg = t >> 5;
    const float4* x4 = (const float4*)x;
    float4 s1 = make_float4(0.f, 0.f, 0.f, 0.f);
    float4 s2 = make_float4(0.f, 0.f, 0.f, 0.f);
    for (int n = blockIdx.x * 8 + rg; n < N; n += gridDim.x * 8) {
        float4 v = x4[(size_t)n * 32 + lane];
        s1.x += v.x; s1.y += v.y; s1.z += v.z; s1.w += v.w;
        s2.x += v.x * v.x; s2.y += v.y * v.y; s2.z += v.z * v.z; s2.w += v.w * v.w;
    }
    r1[t] = s1; r2[t] = s2;
    __syncthreads();
    if (t < 32) {
        float4 a = r1[t], b = r2[t];
        for (int k = 1; k < 8; ++k) {
            float4 c = r1[t + 32 * k], e = r2[t + 32 * k];
            a.x += c.x; a.y += c.y; a.z += c.z; a.w += c.w;
            b.x += e.x; b.y += e.y; b.z += e.z; b.w += e.w;
        }
        atomicAdd(&sums[t * 4 + 0], (double)a.x);
        atomicAdd(&sums[t * 4 + 1], (double)a.y);
        atomicAdd(&sums[t * 4 + 2], (double)a.z);
        atomicAdd(&sums[t * 4 + 3], (double)a.w);
        atomicAdd(&sums[128 + t * 4 + 0], (double)b.x);
        atomicAdd(&sums[128 + t * 4 + 1], (double)b.y);
        atomicAdd(&sums[128 + t * 4 + 2], (double)b.z);
        atomicAdd(&sums[128 + t * 4 + 3], (double)b.w);
    }
}

// ================= pool (BN fold in prologue) =================
__global__ __launch_bounds__(128) void k_pool(const float* __restrict__ x,
        const int* __restrict__ batch,
        const double* __restrict__ bnsum, const float* __restrict__ gamma, const float* __restrict__ beta,
        float* __restrict__ gsum, float* __restrict__ gcnt, int N)
{
    __shared__ __align__(16) float sc_s[128];
    __shared__ __align__(16) float sh_s[128];
    int t = threadIdx.x;
    {
        double mu = bnsum[t] / (double)N;
        double var = bnsum[128 + t] / (double)N - mu * mu;
        if (var < 0.0) var = 0.0;
        double rs = 1.0 / sqrt(var + 1e-5);
        float sc = (float)((double)gamma[t] * rs);
        sc_s[t] = sc;
        sh_s[t] = beta[t] - (float)mu * sc;
    }
    __syncthreads();

    int lane = t & 31;
    int r = t >> 5;
    int n0 = blockIdx.x * 64;
    if (n0 >= N) return;
    int n1 = n0 + 64; if (n1 > N) n1 = N;
    float4 sc = ((const float4*)sc_s)[lane];
    float4 sh = ((const float4*)sh_s)[lane];
    float4 acc = make_float4(0.f, 0.f, 0.f, 0.f);
    int cnt = 0, cur = -1;
    for (int n = n0 + r; n < n1; n += 4) {
        int g = batch[n];
        if (g != cur) {
            if (cur >= 0) {
                atomicAdd(&gsum[cur * 128 + lane * 4 + 0], acc.x);
                atomicAdd(&gsum[cur * 128 + lane * 4 + 1], acc.y);
                atomicAdd(&gsum[cur * 128 + lane * 4 + 2], acc.z);
                atomicAdd(&gsum[cur * 128 + lane * 4 + 3], acc.w);
                if (lane == 0) atomicAdd(&gcnt[cur], (float)cnt);
            }
            acc = make_float4(0.f, 0.f, 0.f, 0.f); cnt = 0; cur = g;
        }
        float4 v = ((const float4*)x)[(size_t)n * 32 + lane];
        v.x = fmaf(v.x, sc.x, sh.x); v.x = v.x > 0.f ? v.x : 0.f;
        v.y = fmaf(v.y, sc.y, sh.y); v.y = v.y > 0.f ? v.y : 0.f;
        v.z = fmaf(v.z, sc.z, sh.z); v.z = v.z > 0.f ? v.z : 0.f;
        v.w = fmaf(v.w, sc.w, sh.w); v.w = v.w > 0.f ? v.w : 0.f;
        acc.x += v.x; acc.y += v.y; acc.z += v.z; acc.w += v.w;
        cnt++;
    }
    if (cur >= 0) {
        atomicAdd(&gsum[cur * 128 + lane * 4 + 0], acc.x);
        atomicAdd(&gsum[cur * 128 + lane * 4 + 1], acc.y);
        atomicAdd(&gsum[cur * 128 + lane * 4 + 2], acc.z);
        atomicAdd(&gsum[cur * 128 + lane * 4 + 3], acc.w);
        if (lane == 0) atomicAdd(&gcnt[cur], (float)cnt);
    }
}

// ================= dense head =================
__global__ __launch_bounds__(256) void k_head(const float* __restrict__ gsum, const float* __restrict__ gcnt,
        const float* __restrict__ d1W, const float* __restrict__ d1b,
        const float* __restrict__ g_d1, const float* __restrict__ b_d1,
        const float* __restrict__ d2W, const float* __restrict__ d2b,
        const float* __restrict__ g_d2, const float* __restrict__ b_d2,
        const float* __restrict__ fcW, const float* __restrict__ fcb,
        float* __restrict__ out)
{
    __shared__ float G[64 * 128];
    __shared__ float Y1[64 * 64];
    __shared__ float Y2[64 * 32];
    int t = threadIdx.x;
    for (int i = t; i < 64 * 128; i += 256) {
        int g = i >> 7;
        float cv = gcnt[g]; if (cv < 1.f) cv = 1.f;
        G[i] = gsum[i] / cv;
    }
    __syncthreads();
    for (int i = t; i < 64 * 64; i += 256) {
        int r = i >> 6, j = i & 63;
        float a = 0.f;
        for (int k = 0; k < 128; ++k) a = fmaf(G[r * 128 + k], d1W[k * 64 + j], a);
        Y1[i] = a + d1b[j];
    }
    __syncthreads();
    if (t < 64) {
        float s1 = 0.f, s2 = 0.f;
        for (int r = 0; r < 64; ++r) { float v = Y1[r * 64 + t]; s1 += v; s2 += v * v; }
        float mu = s1 / 64.f, var = s2 / 64.f - mu * mu; if (var < 0.f) var = 0.f;
        float rs = 1.0f / sqrtf(var + 1e-5f);
        float scv = g_d1[t] * rs, shv = b_d1[t] - mu * scv;
        for (int r = 0; r < 64; ++r) {
            float v = fmaf(Y1[r * 64 + t], scv, shv);
            Y1[r * 64 + t] = v > 0.f ? v : 0.f;
        }
    }
    __syncthreads();
    for (int i = t; i < 64 * 32; i += 256) {
        int r = i >> 5, j = i & 31;
        float a = 0.f;
        for (int k = 0; k < 64; ++k) a = fmaf(Y1[r * 64 + k], d2W[k * 32 + j], a);
        Y2[i] = a + d2b[j];
    }
    __syncthreads();
    if (t < 32) {
        float s1 = 0.f, s2 = 0.f;
        for (int r = 0; r < 64; ++r) { float v = Y2[r * 32 + t]; s1 += v; s2 += v * v; }
        float mu = s1 / 64.f, var = s2 / 64.f - mu * mu; if (var < 0.f) var = 0.f;
        float rs = 1.0f / sqrtf(var + 1e-5f);
        float scv = g_d2[t] * rs, shv = b_d2[t] - mu * scv;
        for (int r = 0; r < 64; ++r) {
            float v = fmaf(Y2[r * 32 + t], scv, shv);
            Y2[r * 32 + t] = v > 0.f ? v : 0.f;
        }
    }
    __syncthreads();
    {
        int r = t >> 2, j = t & 3;
        float a = 0.f;
        for (int k = 0; k < 32; ++k) a = fmaf(Y2[r * 32 + k], fcW[k * 4 + j], a);
        out[t] = a + fcb[j];
    }
}

extern "C" void kernel_launch(void* const* d_in, const int* in_sizes, int n_in,
                              void* d_out, int out_size, void* d_ws, size_t ws_size,
                              hipStream_t stream) {
    const int N = in_sizes[0] / 16;
    const int E = in_sizes[1] / 2;
    const int nB = (N + 255) >> 8;

    const float* x        = (const float*)d_in[0];
    const int*   ei       = (const int*)d_in[1];
    const int*   batch    = (const int*)d_in[2];
    const float* W1       = (const float*)d_in[3];
    const float* att_s1   = (const float*)d_in[5];
    const float* att_d1   = (const float*)d_in[6];
    const float* bn_g1    = (const float*)d_in[7];
    const float* bn_b1    = (const float*)d_in[8];
    const float* W2       = (const float*)d_in[9];
    const float* att_s2   = (const float*)d_in[11];
    const float* att_d2   = (const float*)d_in[12];
    const float* bn_g2    = (const float*)d_in[13];
    const float* bn_b2    = (const float*)d_in[14];
    const float* d1W      = (const float*)d_in[15];
    const float* d1b      = (const float*)d_in[16];
    const float* g_d1     = (const float*)d_in[17];
    const float* b_d1     = (const float*)d_in[18];
    const float* d2W      = (const float*)d_in[19];
    const float* d2b      = (const float*)d_in[20];
    const float* g_d2     = (const float*)d_in[21];
    const float* b_d2     = (const float*)d_in[22];
    const float* fcW      = (const float*)d_in[23];
    const float* fcb      = (const float*)d_in[24];
    float* out = (float*)d_out;

    float* ws = (float*)d_ws;
    size_t o = 0;
    unsigned short* hbuf = (unsigned short*)(ws + o); o += (size_t)N * 64;  // N*128 bf16
    float* outb   = ws + o;  o += (size_t)N * 128;
    float* as_    = ws + o;  o += (size_t)N * 4;
    float* ad_    = ws + o;  o += (size_t)N * 4;
    // ---- zero region (one memset): bnsumA, bnsumB, gsum, gcnt, bSize ----
    size_t zoff = o;
    double* bnsumA = (double*)(ws + o); o += 512;
    double* bnsumB = (double*)(ws + o); o += 512;
    float* gsum   = ws + o;  o += 64 * 128;
    float* gcnt   = ws + o;  o += 64;
    int*   bSize  = (int*)(ws + o); o += 1024;
    size_t zbytes = (o - zoff) * 4;
    int* rowPtr   = (int*)(ws + o); o += (size_t)N + 1;
    int* sSrc     = (int*)(ws + o); o += E;
    int* bOff     = (int*)(ws + o); o += 1025;
    int* bCur     = (int*)(ws + o); o += 1024;
    unsigned int* bucketBuf = (unsigned int*)(ws + o); o += E;

    hipMemsetAsync(ws + zoff, 0, zbytes, stream);

    // ---- CSR build (bucket radix, shared by both layers) ----
    k_bhist<<<256, 256, 0, stream>>>(ei, bSize, E, nB);
    k_bscan<<<1, 512, 0, stream>>>(bSize, bOff, bCur, nB);
    k_part<<<256, 256, 0, stream>>>(ei, bCur, bucketBuf, E, nB);
    k_build<<<nB, 256, 0, stream>>>(bucketBuf, bOff, rowPtr, sSrc, N);

    int gemm_grid = (N + 63) / 64;
    int agg_grid = (N + 15) / 16;

    // ---- layer 1 ----
    k_gemm<16, false><<<gemm_grid, 256, 0, stream>>>(x, W1, nullptr, nullptr, nullptr,
            att_s1, att_d1, hbuf, as_, ad_, N);
    k_agg<<<agg_grid, 256, 0, stream>>>(rowPtr, sSrc, as_, ad_, hbuf, outb, N);
    k_bnstats<<<512, 256, 0, stream>>>(outb, bnsumA, N);

    // ---- layer 2 (BN1 folded into gemm prologue) ----
    k_gemm<128, true><<<gemm_grid, 256, 0, stream>>>(outb, W2, bnsumA, bn_g1, bn_b1,
            att_s2, att_d2, hbuf, as_, ad_, N);
    k_agg<<<agg_grid, 256, 0, stream>>>(rowPtr, sSrc, as_, ad_, hbuf, outb, N);
    k_bnstats<<<512, 256, 0, stream>>>(outb, bnsumB, N);

    // ---- pool (BN2 folded) + head ----
    k_pool<<<(N + 63) / 64, 128, 0, stream>>>(outb, batch, bnsumB, bn_g2, bn_b2, gsum, gcnt, N);
    k_head<<<1, 256, 0, stream>>>(gsum, gcnt, d1W, d1b, g_d1, b_d1,
                                  d2W, d2b, g_d2, b_d2, fcW, fcb, out);
}

// Round 10
// 571.914 us; speedup vs baseline: 1.0592x; 1.0039x over previous
//
#include <hip/hip_runtime.h>

#define HID 128
#define NG 64

__device__ __forceinline__ float lrelu(float v) { return v > 0.0f ? v : 0.2f * v; }

__device__ __forceinline__ unsigned int bf16rne(float f) {
    unsigned int u = __float_as_uint(f);
    return (u + 0x7fffu + ((u >> 16) & 1u)) >> 16;
}
__device__ __forceinline__ unsigned int packbf(float a, float b) {
    return bf16rne(a) | (bf16rne(b) << 16);
}
__device__ __forceinline__ float bflo(unsigned int u) { return __uint_as_float(u << 16); }
__device__ __forceinline__ float bfhi(unsigned int u) { return __uint_as_float(u & 0xffff0000u); }

// ================= layer-1 GEMM: f32 x[N,16] -> bf16 h, as_, ad_ =================
__global__ __launch_bounds__(256) void k_gemm1(const float* __restrict__ xin,
        const float* __restrict__ W,
        const float* __restrict__ attS, const float* __restrict__ attD,
        unsigned short* __restrict__ h, float* __restrict__ as_, float* __restrict__ ad_, int N)
{
    __shared__ float xs[64][16];
    int t = threadIdx.x;
    int cq = t & 31;
    int nr = t >> 5;

    float4 atS = ((const float4*)attS)[cq];
    float4 atD = ((const float4*)attD)[cq];

    for (int n0 = blockIdx.x * 64; n0 < N; n0 += gridDim.x * 64) {
        int nrem = N - n0; if (nrem > 64) nrem = 64;
        for (int idx = t; idx < 64 * 4; idx += 256) {
            int n = idx >> 2, k4 = idx & 3;
            float4 v = make_float4(0.f, 0.f, 0.f, 0.f);
            if (n < nrem) v = ((const float4*)(xin + (size_t)(n0 + n) * 16))[k4];
            *(float4*)(&xs[n][k4 * 4]) = v;
        }
        __syncthreads();

        float4 acc[8];
#pragma unroll
        for (int j = 0; j < 8; ++j) acc[j] = make_float4(0.f, 0.f, 0.f, 0.f);

        const float4* W4 = (const float4*)W;
#pragma unroll
        for (int k4 = 0; k4 < 4; ++k4) {
            float4 w0 = W4[(k4 * 4 + 0) * 32 + cq];
            float4 w1 = W4[(k4 * 4 + 1) * 32 + cq];
            float4 w2 = W4[(k4 * 4 + 2) * 32 + cq];
            float4 w3 = W4[(k4 * 4 + 3) * 32 + cq];
#pragma unroll
            for (int j = 0; j < 8; ++j) {
                float4 xv = *(const float4*)(&xs[nr * 8 + j][k4 * 4]);
                acc[j].x = fmaf(xv.x, w0.x, acc[j].x);
                acc[j].y = fmaf(xv.x, w0.y, acc[j].y);
                acc[j].z = fmaf(xv.x, w0.z, acc[j].z);
                acc[j].w = fmaf(xv.x, w0.w, acc[j].w);
                acc[j].x = fmaf(xv.y, w1.x, acc[j].x);
                acc[j].y = fmaf(xv.y, w1.y, acc[j].y);
                acc[j].z = fmaf(xv.y, w1.z, acc[j].z);
                acc[j].w = fmaf(xv.y, w1.w, acc[j].w);
                acc[j].x = fmaf(xv.z, w2.x, acc[j].x);
                acc[j].y = fmaf(xv.z, w2.y, acc[j].y);
                acc[j].z = fmaf(xv.z, w2.z, acc[j].z);
                acc[j].w = fmaf(xv.z, w2.w, acc[j].w);
                acc[j].x = fmaf(xv.w, w3.x, acc[j].x);
                acc[j].y = fmaf(xv.w, w3.y, acc[j].y);
                acc[j].z = fmaf(xv.w, w3.z, acc[j].z);
                acc[j].w = fmaf(xv.w, w3.w, acc[j].w);
            }
        }

#pragma unroll
        for (int j = 0; j < 8; ++j) {
            int n = nr * 8 + j;
            bool ok = (n < nrem);
            if (ok) {
                unsigned int lo = packbf(acc[j].x, acc[j].y);
                unsigned int hi = packbf(acc[j].z, acc[j].w);
                ((uint2*)(h + (size_t)(n0 + n) * 128))[cq] = make_uint2(lo, hi);
            }
            float ps = acc[j].x * atS.x + acc[j].y * atS.y + acc[j].z * atS.z + acc[j].w * atS.w;
            float pd = acc[j].x * atD.x + acc[j].y * atD.y + acc[j].z * atD.z + acc[j].w * atD.w;
            ps += __shfl_xor(ps, 1); pd += __shfl_xor(pd, 1);
            ps += __shfl_xor(ps, 2); pd += __shfl_xor(pd, 2);
            ps += __shfl_xor(ps, 4); pd += __shfl_xor(pd, 4);
            if (ok && (cq & 7) == 0) {
                int hd = cq >> 3;
                as_[(size_t)(n0 + n) * 4 + hd] = ps;
                ad_[(size_t)(n0 + n) * 4 + hd] = pd;
            }
        }
        __syncthreads();
    }
}

// ================= layer-2 GEMM: bf16 in (BN fold in prologue) -> bf16 h =================
__global__ __launch_bounds__(256) void k_gemm2(const unsigned short* __restrict__ xin,
        const float* __restrict__ W,
        const double* __restrict__ bnsum, const float* __restrict__ gamma, const float* __restrict__ beta,
        const float* __restrict__ attS, const float* __restrict__ attD,
        unsigned short* __restrict__ h, float* __restrict__ as_, float* __restrict__ ad_, int N)
{
    __shared__ float xs[64][128];
    __shared__ __align__(16) float sc_s[128];
    __shared__ __align__(16) float sh_s[128];
    int t = threadIdx.x;
    int cq = t & 31;
    int nr = t >> 5;

    if (t < 128) {
        double mu = bnsum[t] / (double)N;
        double var = bnsum[128 + t] / (double)N - mu * mu;
        if (var < 0.0) var = 0.0;
        double rs = 1.0 / sqrt(var + 1e-5);
        float sc = (float)((double)gamma[t] * rs);
        sc_s[t] = sc;
        sh_s[t] = beta[t] - (float)mu * sc;
    }
    __syncthreads();

    float4 atS = ((const float4*)attS)[cq];
    float4 atD = ((const float4*)attD)[cq];
    const uint2* x2 = (const uint2*)xin;

    for (int n0 = blockIdx.x * 64; n0 < N; n0 += gridDim.x * 64) {
        int nrem = N - n0; if (nrem > 64) nrem = 64;
        for (int idx = t; idx < 64 * 32; idx += 256) {
            int n = idx >> 5, k8 = idx & 31;   // k8 = uint2 unit = 4 channels
            float4 v = make_float4(0.f, 0.f, 0.f, 0.f);
            if (n < nrem) {
                uint2 u = x2[(size_t)(n0 + n) * 32 + k8];
                float4 sc = ((const float4*)sc_s)[k8];
                float4 sh = ((const float4*)sh_s)[k8];
                v.x = fmaf(bflo(u.x), sc.x, sh.x); v.x = v.x > 0.f ? v.x : 0.f;
                v.y = fmaf(bfhi(u.x), sc.y, sh.y); v.y = v.y > 0.f ? v.y : 0.f;
                v.z = fmaf(bflo(u.y), sc.z, sh.z); v.z = v.z > 0.f ? v.z : 0.f;
                v.w = fmaf(bfhi(u.y), sc.w, sh.w); v.w = v.w > 0.f ? v.w : 0.f;
            }
            *(float4*)(&xs[n][k8 * 4]) = v;
        }
        __syncthreads();

        float4 acc[8];
#pragma unroll
        for (int j = 0; j < 8; ++j) acc[j] = make_float4(0.f, 0.f, 0.f, 0.f);

        const float4* W4 = (const float4*)W;
#pragma unroll 2
        for (int k4 = 0; k4 < 32; ++k4) {
            float4 w0 = W4[(k4 * 4 + 0) * 32 + cq];
            float4 w1 = W4[(k4 * 4 + 1) * 32 + cq];
            float4 w2 = W4[(k4 * 4 + 2) * 32 + cq];
            float4 w3 = W4[(k4 * 4 + 3) * 32 + cq];
#pragma unroll
            for (int j = 0; j < 8; ++j) {
                float4 xv = *(const float4*)(&xs[nr * 8 + j][k4 * 4]);
                acc[j].x = fmaf(xv.x, w0.x, acc[j].x);
                acc[j].y = fmaf(xv.x, w0.y, acc[j].y);
                acc[j].z = fmaf(xv.x, w0.z, acc[j].z);
                acc[j].w = fmaf(xv.x, w0.w, acc[j].w);
                acc[j].x = fmaf(xv.y, w1.x, acc[j].x);
                acc[j].y = fmaf(xv.y, w1.y, acc[j].y);
                acc[j].z = fmaf(xv.y, w1.z, acc[j].z);
                acc[j].w = fmaf(xv.y, w1.w, acc[j].w);
                acc[j].x = fmaf(xv.z, w2.x, acc[j].x);
                acc[j].y = fmaf(xv.z, w2.y, acc[j].y);
                acc[j].z = fmaf(xv.z, w2.z, acc[j].z);
                acc[j].w = fmaf(xv.z, w2.w, acc[j].w);
                acc[j].x = fmaf(xv.w, w3.x, acc[j].x);
                acc[j].y = fmaf(xv.w, w3.y, acc[j].y);
                acc[j].z = fmaf(xv.w, w3.z, acc[j].z);
                acc[j].w = fmaf(xv.w, w3.w, acc[j].w);
            }
        }

#pragma unroll
        for (int j = 0; j < 8; ++j) {
            int n = nr * 8 + j;
            bool ok = (n < nrem);
            if (ok) {
                unsigned int lo = packbf(acc[j].x, acc[j].y);
                unsigned int hi = packbf(acc[j].z, acc[j].w);
                ((uint2*)(h + (size_t)(n0 + n) * 128))[cq] = make_uint2(lo, hi);
            }
            float ps = acc[j].x * atS.x + acc[j].y * atS.y + acc[j].z * atS.z + acc[j].w * atS.w;
            float pd = acc[j].x * atD.x + acc[j].y * atD.y + acc[j].z * atD.z + acc[j].w * atD.w;
            ps += __shfl_xor(ps, 1); pd += __shfl_xor(pd, 1);
            ps += __shfl_xor(ps, 2); pd += __shfl_xor(pd, 2);
            ps += __shfl_xor(ps, 4); pd += __shfl_xor(pd, 4);
            if (ok && (cq & 7) == 0) {
                int hd = cq >> 3;
                as_[(size_t)(n0 + n) * 4 + hd] = ps;
                ad_[(size_t)(n0 + n) * 4 + hd] = pd;
            }
        }
        __syncthreads();
    }
}

// ================= CSR build: bucket radix (bucket = dst >> 8), packed 4B =================
__global__ __launch_bounds__(256) void k_bhist(const int* __restrict__ ei,
        int* __restrict__ bSize, int E, int nB)
{
    __shared__ int hist[1024];
    int t = threadIdx.x;
    for (int i = t; i < nB; i += 256) hist[i] = 0;
    __syncthreads();
    int chunk = (E + gridDim.x - 1) / gridDim.x;
    int lo = blockIdx.x * chunk, hi = lo + chunk; if (hi > E) hi = E;
    for (int e = lo + t; e < hi; e += 256) atomicAdd(&hist[ei[E + e] >> 8], 1);
    __syncthreads();
    for (int i = t; i < nB; i += 256) { int c = hist[i]; if (c) atomicAdd(&bSize[i], c); }
}

__global__ __launch_bounds__(512) void k_bscan(const int* __restrict__ bSize,
        int* __restrict__ bOff, int* __restrict__ bCur, int nB)
{
    __shared__ int part[512];
    int t = threadIdx.x;
    part[t] = (t < nB) ? bSize[t] : 0;
    __syncthreads();
    for (int off = 1; off < 512; off <<= 1) {
        int u = (t >= off) ? part[t - off] : 0;
        __syncthreads();
        part[t] += u;
        __syncthreads();
    }
    int ex = (t == 0) ? 0 : part[t - 1];
    if (t < nB) { bOff[t] = ex; bCur[t] = ex; }
    if (t == nB - 1) bOff[nB] = part[t];
}

__global__ __launch_bounds__(256) void k_part(const int* __restrict__ ei,
        int* __restrict__ bCur, unsigned int* __restrict__ bucketBuf, int E, int nB)
{
    __shared__ int hist[1024];
    __shared__ int base[1024];
    int t = threadIdx.x;
    int chunk = (E + gridDim.x - 1) / gridDim.x;
    int lo = blockIdx.x * chunk, hi = lo + chunk; if (hi > E) hi = E;
    for (int i = t; i < nB; i += 256) hist[i] = 0;
    __syncthreads();
    for (int e = lo + t; e < hi; e += 256) atomicAdd(&hist[ei[E + e] >> 8], 1);
    __syncthreads();
    for (int i = t; i < nB; i += 256) {
        int c = hist[i];
        base[i] = c ? atomicAdd(&bCur[i], c) : 0;
        hist[i] = 0;
    }
    __syncthreads();
    for (int e = lo + t; e < hi; e += 256) {
        int s = ei[e], d = ei[E + e];
        int b = d >> 8;
        int pos = base[b] + atomicAdd(&hist[b], 1);
        bucketBuf[pos] = ((unsigned)(d & 255) << 24) | (unsigned)s;  // N < 2^24
    }
}

__global__ __launch_bounds__(256) void k_build(const unsigned int* __restrict__ bucketBuf,
        const int* __restrict__ bOff, int* __restrict__ rowPtr, int* __restrict__ sSrc, int N)
{
    __shared__ int lhist[256];
    __shared__ int sOut[8192];
    int b = blockIdx.x;
    int dlo = b << 8;
    int dhi = dlo + 256; if (dhi > N) dhi = N;
    int base = bOff[b], end = bOff[b + 1];
    int sz = end - base;
    int t = threadIdx.x;
    lhist[t] = 0;
    __syncthreads();
    for (int i = t; i < sz; i += 256) {
        atomicAdd(&lhist[bucketBuf[base + i] >> 24], 1);
    }
    __syncthreads();
    for (int off = 1; off < 256; off <<= 1) {
        int u = (t >= off) ? lhist[t - off] : 0;
        __syncthreads();
        lhist[t] += u;
        __syncthreads();
    }
    int pfx = (t == 0) ? 0 : lhist[t - 1];
    if (dlo + t < dhi) rowPtr[dlo + t] = base + pfx;
    if (t == 0 && dhi == N) rowPtr[N] = end;
    __syncthreads();
    lhist[t] = pfx;
    __syncthreads();
    if (sz <= 8192) {
        for (int i = t; i < sz; i += 256) {
            unsigned int p = bucketBuf[base + i];
            int pos = atomicAdd(&lhist[p >> 24], 1);
            sOut[pos] = (int)(p & 0xffffffu);
        }
        __syncthreads();
        for (int i = t; i < sz; i += 256) sSrc[base + i] = sOut[i];
    } else {
        for (int i = t; i < sz; i += 256) {
            unsigned int p = bucketBuf[base + i];
            int pos = atomicAdd(&lhist[p >> 24], 1);
            sSrc[base + pos] = (int)(p & 0xffffffu);
        }
    }
}

// ================= fused softmax + CSR SpMM aggregation (16 lanes/dst, bf16 out) =================
__global__ __launch_bounds__(256) void k_agg(const int* __restrict__ rowPtr,
        const int* __restrict__ sSrc,
        const float* __restrict__ as_, const float* __restrict__ ad_,
        const unsigned short* __restrict__ h, unsigned short* __restrict__ out, int N)
{
    int t = threadIdx.x;
    int l = t & 15;
    int d = blockIdx.x * 16 + (t >> 4);
    if (d >= N) return;
    int hd = l >> 2;
    int b0 = rowPtr[d], b1 = rowPtr[d + 1];
    float4 adv = ((const float4*)ad_)[d];

    // pass 1: per-head sums of exp(lrelu(as+ad))
    float4 sm = make_float4(0.f, 0.f, 0.f, 0.f);
    for (int j = b0 + l; j < b1; j += 16) {
        int s = sSrc[j];
        float4 a = ((const float4*)as_)[s];
        sm.x += __expf(lrelu(a.x + adv.x));
        sm.y += __expf(lrelu(a.y + adv.y));
        sm.z += __expf(lrelu(a.z + adv.z));
        sm.w += __expf(lrelu(a.w + adv.w));
    }
#pragma unroll
    for (int off = 1; off < 16; off <<= 1) {
        sm.x += __shfl_xor(sm.x, off);
        sm.y += __shfl_xor(sm.y, off);
        sm.z += __shfl_xor(sm.z, off);
        sm.w += __shfl_xor(sm.w, off);
    }
    float sumh = (hd == 0) ? sm.x : (hd == 1) ? sm.y : (hd == 2) ? sm.z : sm.w;
    float advh = (hd == 0) ? adv.x : (hd == 1) ? adv.y : (hd == 2) ? adv.z : adv.w;
    float inv = 1.f / (sumh + 1e-16f);

    const uint4* h4 = (const uint4*)h;   // row = 16 x uint4
    float4 acc0 = make_float4(0.f, 0.f, 0.f, 0.f);
    float4 acc1 = make_float4(0.f, 0.f, 0.f, 0.f);
#define AGG1(S, W) { uint4 u = h4[(size_t)(S) * 16 + l]; \
        acc0.x = fmaf((W), bflo(u.x), acc0.x); \
        acc0.y = fmaf((W), bfhi(u.x), acc0.y); \
        acc0.z = fmaf((W), bflo(u.y), acc0.z); \
        acc0.w = fmaf((W), bfhi(u.y), acc0.w); \
        acc1.x = fmaf((W), bflo(u.z), acc1.x); \
        acc1.y = fmaf((W), bfhi(u.z), acc1.y); \
        acc1.z = fmaf((W), bflo(u.w), acc1.z); \
        acc1.w = fmaf((W), bfhi(u.w), acc1.w); }
    int j = b0;
    for (; j + 4 <= b1; j += 4) {
        int s0 = sSrc[j], s1 = sSrc[j + 1], s2 = sSrc[j + 2], s3 = sSrc[j + 3];
        float w0 = __expf(lrelu(as_[(size_t)s0 * 4 + hd] + advh));
        float w1 = __expf(lrelu(as_[(size_t)s1 * 4 + hd] + advh));
        float w2 = __expf(lrelu(as_[(size_t)s2 * 4 + hd] + advh));
        float w3 = __expf(lrelu(as_[(size_t)s3 * 4 + hd] + advh));
        uint4 u0 = h4[(size_t)s0 * 16 + l];
        uint4 u1 = h4[(size_t)s1 * 16 + l];
        uint4 u2 = h4[(size_t)s2 * 16 + l];
        uint4 u3 = h4[(size_t)s3 * 16 + l];
        acc0.x = fmaf(w0, bflo(u0.x), acc0.x);
        acc0.y = fmaf(w0, bfhi(u0.x), acc0.y);
        acc0.z = fmaf(w0, bflo(u0.y), acc0.z);
        acc0.w = fmaf(w0, bfhi(u0.y), acc0.w);
        acc1.x = fmaf(w0, bflo(u0.z), acc1.x);
        acc1.y = fmaf(w0, bfhi(u0.z), acc1.y);
        acc1.z = fmaf(w0, bflo(u0.w), acc1.z);
        acc1.w = fmaf(w0, bfhi(u0.w), acc1.w);
        acc0.x = fmaf(w1, bflo(u1.x), acc0.x);
        acc0.y = fmaf(w1, bfhi(u1.x), acc0.y);
        acc0.z = fmaf(w1, bflo(u1.y), acc0.z);
        acc0.w = fmaf(w1, bfhi(u1.y), acc0.w);
        acc1.x = fmaf(w1, bflo(u1.z), acc1.x);
        acc1.y = fmaf(w1, bfhi(u1.z), acc1.y);
        acc1.z = fmaf(w1, bflo(u1.w), acc1.z);
        acc1.w = fmaf(w1, bfhi(u1.w), acc1.w);
        acc0.x = fmaf(w2, bflo(u2.x), acc0.x);
        acc0.y = fmaf(w2, bfhi(u2.x), acc0.y);
        acc0.z = fmaf(w2, bflo(u2.y), acc0.z);
        acc0.w = fmaf(w2, bfhi(u2.y), acc0.w);
        acc1.x = fmaf(w2, bflo(u2.z), acc1.x);
        acc1.y = fmaf(w2, bfhi(u2.z), acc1.y);
        acc1.z = fmaf(w2, bflo(u2.w), acc1.z);
        acc1.w = fmaf(w2, bfhi(u2.w), acc1.w);
        acc0.x = fmaf(w3, bflo(u3.x), acc0.x);
        acc0.y = fmaf(w3, bfhi(u3.x), acc0.y);
        acc0.z = fmaf(w3, bflo(u3.y), acc0.z);
        acc0.w = fmaf(w3, bfhi(u3.y), acc0.w);
        acc1.x = fmaf(w3, bflo(u3.z), acc1.x);
        acc1.y = fmaf(w3, bfhi(u3.z), acc1.y);
        acc1.z = fmaf(w3, bflo(u3.w), acc1.z);
        acc1.w = fmaf(w3, bfhi(u3.w), acc1.w);
    }
    for (; j < b1; ++j) {
        int s = sSrc[j];
        float w = __expf(lrelu(as_[(size_t)s * 4 + hd] + advh));
        AGG1(s, w);
    }
#undef AGG1
    acc0.x *= inv; acc0.y *= inv; acc0.z *= inv; acc0.w *= inv;
    acc1.x *= inv; acc1.y *= inv; acc1.z *= inv; acc1.w *= inv;
    unsigned int p0 = packbf(acc0.x, acc0.y);
    unsigned int p1 = packbf(acc0.z, acc0.w);
    unsigned int p2 = packbf(acc1.x, acc1.y);
    unsigned int p3 = packbf(acc1.z, acc1.w);
    ((uint4*)out)[(size_t)d * 16 + l] = make_uint4(p0, p1, p2, p3);
}

// ================= BN stats (bf16 input, uint2 lanes, LDS tree, f64 atomics) =================
__global__ __launch_bounds__(256) void k_bnstats(const unsigned short* __restrict__ x,
        double* __restrict__ sums, int N)
{
    __shared__ float4 r1[256], r2[256];
    int t = threadIdx.x;
    int lane = t & 31;
    int rg = t >> 5;
    const uint2* x2 = (const uint2*)x;
    float4 s1 = make_float4(0.f, 0.f, 0.f, 0.f);
    float4 s2 = make_float4(0.f, 0.f, 0.f, 0.f);
    for (int n = blockIdx.x * 8 + rg; n < N; n += gridDim.x * 8) {
        uint2 u = x2[(size_t)n * 32 + lane];
        float a = bflo(u.x), b = bfhi(u.x), c = bflo(u.y), e = bfhi(u.y);
        s1.x += a; s1.y += b; s1.z += c; s1.w += e;
        s2.x += a * a; s2.y += b * b; s2.z += c * c; s2.w += e * e;
    }
    r1[t] = s1; r2[t] = s2;
    __syncthreads();
    if (t < 32) {
        float4 a = r1[t], b = r2[t];
        for (int k = 1; k < 8; ++k) {
            float4 c = r1[t + 32 * k], e = r2[t + 32 * k];
            a.x += c.x; a.y += c.y; a.z += c.z; a.w += c.w;
            b.x += e.x; b.y += e.y; b.z += e.z; b.w += e.w;
        }
        atomicAdd(&sums[t * 4 + 0], (double)a.x);
        atomicAdd(&sums[t * 4 + 1], (double)a.y);
        atomicAdd(&sums[t * 4 + 2], (double)a.z);
        atomicAdd(&sums[t * 4 + 3], (double)a.w);
        atomicAdd(&sums[128 + t * 4 + 0], (double)b.x);
        atomicAdd(&sums[128 + t * 4 + 1], (double)b.y);
        atomicAdd(&sums[128 + t * 4 + 2], (double)b.z);
        atomicAdd(&sums[128 + t * 4 + 3], (double)b.w);
    }
}

// ================= pool (bf16 input, BN fold in prologue) =================
__global__ __launch_bounds__(128) void k_pool(const unsigned short* __restrict__ x,
        const int* __restrict__ batch,
        const double* __restrict__ bnsum, const float* __restrict__ gamma, const float* __restrict__ beta,
        float* __restrict__ gsum, float* __restrict__ gcnt, int N)
{
    __shared__ __align__(16) float sc_s[128];
    __shared__ __align__(16) float sh_s[128];
    int t = threadIdx.x;
    {
        double mu = bnsum[t] / (double)N;
        double var = bnsum[128 + t] / (double)N - mu * mu;
        if (var < 0.0) var = 0.0;
        double rs = 1.0 / sqrt(var + 1e-5);
        float sc = (float)((double)gamma[t] * rs);
        sc_s[t] = sc;
        sh_s[t] = beta[t] - (float)mu * sc;
    }
    __syncthreads();

    int lane = t & 31;
    int r = t >> 5;
    int n0 = blockIdx.x * 64;
    if (n0 >= N) return;
    int n1 = n0 + 64; if (n1 > N) n1 = N;
    float4 sc = ((const float4*)sc_s)[lane];
    float4 sh = ((const float4*)sh_s)[lane];
    const uint2* x2 = (const uint2*)x;
    float4 acc = make_float4(0.f, 0.f, 0.f, 0.f);
    int cnt = 0, cur = -1;
    for (int n = n0 + r; n < n1; n += 4) {
        int g = batch[n];
        if (g != cur) {
            if (cur >= 0) {
                atomicAdd(&gsum[cur * 128 + lane * 4 + 0], acc.x);
                atomicAdd(&gsum[cur * 128 + lane * 4 + 1], acc.y);
                atomicAdd(&gsum[cur * 128 + lane * 4 + 2], acc.z);
                atomicAdd(&gsum[cur * 128 + lane * 4 + 3], acc.w);
                if (lane == 0) atomicAdd(&gcnt[cur], (float)cnt);
            }
            acc = make_float4(0.f, 0.f, 0.f, 0.f); cnt = 0; cur = g;
        }
        uint2 u = x2[(size_t)n * 32 + lane];
        float4 v = make_float4(bflo(u.x), bfhi(u.x), bflo(u.y), bfhi(u.y));
        v.x = fmaf(v.x, sc.x, sh.x); v.x = v.x > 0.f ? v.x : 0.f;
        v.y = fmaf(v.y, sc.y, sh.y); v.y = v.y > 0.f ? v.y : 0.f;
        v.z = fmaf(v.z, sc.z, sh.z); v.z = v.z > 0.f ? v.z : 0.f;
        v.w = fmaf(v.w, sc.w, sh.w); v.w = v.w > 0.f ? v.w : 0.f;
        acc.x += v.x; acc.y += v.y; acc.z += v.z; acc.w += v.w;
        cnt++;
    }
    if (cur >= 0) {
        atomicAdd(&gsum[cur * 128 + lane * 4 + 0], acc.x);
        atomicAdd(&gsum[cur * 128 + lane * 4 + 1], acc.y);
        atomicAdd(&gsum[cur * 128 + lane * 4 + 2], acc.z);
        atomicAdd(&gsum[cur * 128 + lane * 4 + 3], acc.w);
        if (lane == 0) atomicAdd(&gcnt[cur], (float)cnt);
    }
}

// ================= dense head =================
__global__ __launch_bounds__(256) void k_head(const float* __restrict__ gsum, const float* __restrict__ gcnt,
        const float* __restrict__ d1W, const float* __restrict__ d1b,
        const float* __restrict__ g_d1, const float* __restrict__ b_d1,
        const float* __restrict__ d2W, const float* __restrict__ d2b,
        const float* __restrict__ g_d2, const float* __restrict__ b_d2,
        const float* __restrict__ fcW, const float* __restrict__ fcb,
        float* __restrict__ out)
{
    __shared__ float G[64 * 128];
    __shared__ float Y1[64 * 64];
    __shared__ float Y2[64 * 32];
    int t = threadIdx.x;
    for (int i = t; i < 64 * 128; i += 256) {
        int g = i >> 7;
        float cv = gcnt[g]; if (cv < 1.f) cv = 1.f;
        G[i] = gsum[i] / cv;
    }
    __syncthreads();
    for (int i = t; i < 64 * 64; i += 256) {
        int r = i >> 6, j = i & 63;
        float a = 0.f;
        for (int k = 0; k < 128; ++k) a = fmaf(G[r * 128 + k], d1W[k * 64 + j], a);
        Y1[i] = a + d1b[j];
    }
    __syncthreads();
    if (t < 64) {
        float s1 = 0.f, s2 = 0.f;
        for (int r = 0; r < 64; ++r) { float v = Y1[r * 64 + t]; s1 += v; s2 += v * v; }
        float mu = s1 / 64.f, var = s2 / 64.f - mu * mu; if (var < 0.f) var = 0.f;
        float rs = 1.0f / sqrtf(var + 1e-5f);
        float scv = g_d1[t] * rs, shv = b_d1[t] - mu * scv;
        for (int r = 0; r < 64; ++r) {
            float v = fmaf(Y1[r * 64 + t], scv, shv);
            Y1[r * 64 + t] = v > 0.f ? v : 0.f;
        }
    }
    __syncthreads();
    for (int i = t; i < 64 * 32; i += 256) {
        int r = i >> 5, j = i & 31;
        float a = 0.f;
        for (int k = 0; k < 64; ++k) a = fmaf(Y1[r * 64 + k], d2W[k * 32 + j], a);
        Y2[i] = a + d2b[j];
    }
    __syncthreads();
    if (t < 32) {
        float s1 = 0.f, s2 = 0.f;
        for (int r = 0; r < 64; ++r) { float v = Y2[r * 32 + t]; s1 += v; s2 += v * v; }
        float mu = s1 / 64.f, var = s2 / 64.f - mu * mu; if (var < 0.f) var = 0.f;
        float rs = 1.0f / sqrtf(var + 1e-5f);
        float scv = g_d2[t] * rs, shv = b_d2[t] - mu * scv;
        for (int r = 0; r < 64; ++r) {
            float v = fmaf(Y2[r * 32 + t], scv, shv);
            Y2[r * 32 + t] = v > 0.f ? v : 0.f;
        }
    }
    __syncthreads();
    {
        int r = t >> 2, j = t & 3;
        float a = 0.f;
        for (int k = 0; k < 32; ++k) a = fmaf(Y2[r * 32 + k], fcW[k * 4 + j], a);
        out[t] = a + fcb[j];
    }
}

extern "C" void kernel_launch(void* const* d_in, const int* in_sizes, int n_in,
                              void* d_out, int out_size, void* d_ws, size_t ws_size,
                              hipStream_t stream) {
    const int N = in_sizes[0] / 16;
    const int E = in_sizes[1] / 2;
    const int nB = (N + 255) >> 8;

    const float* x        = (const float*)d_in[0];
    const int*   ei       = (const int*)d_in[1];
    const int*   batch    = (const int*)d_in[2];
    const float* W1       = (const float*)d_in[3];
    const float* att_s1   = (const float*)d_in[5];
    const float* att_d1   = (const float*)d_in[6];
    const float* bn_g1    = (const float*)d_in[7];
    const float* bn_b1    = (const float*)d_in[8];
    const float* W2       = (const float*)d_in[9];
    const float* att_s2   = (const float*)d_in[11];
    const float* att_d2   = (const float*)d_in[12];
    const float* bn_g2    = (const float*)d_in[13];
    const float* bn_b2    = (const float*)d_in[14];
    const float* d1W      = (const float*)d_in[15];
    const float* d1b      = (const float*)d_in[16];
    const float* g_d1     = (const float*)d_in[17];
    const float* b_d1     = (const float*)d_in[18];
    const float* d2W      = (const float*)d_in[19];
    const float* d2b      = (const float*)d_in[20];
    const float* g_d2     = (const float*)d_in[21];
    const float* b_d2     = (const float*)d_in[22];
    const float* fcW      = (const float*)d_in[23];
    const float* fcb      = (const float*)d_in[24];
    float* out = (float*)d_out;

    float* ws = (float*)d_ws;
    size_t o = 0;
    unsigned short* hbuf = (unsigned short*)(ws + o); o += (size_t)N * 64;  // N*128 bf16
    unsigned short* outb = (unsigned short*)(ws + o); o += (size_t)N * 64;  // N*128 bf16
    float* as_    = ws + o;  o += (size_t)N * 4;
    float* ad_    = ws + o;  o += (size_t)N * 4;
    // ---- zero region (one memset): bnsumA, bnsumB, gsum, gcnt, bSize ----
    size_t zoff = o;
    double* bnsumA = (double*)(ws + o); o += 512;
    double* bnsumB = (double*)(ws + o); o += 512;
    float* gsum   = ws + o;  o += 64 * 128;
    float* gcnt   = ws + o;  o += 64;
    int*   bSize  = (int*)(ws + o); o += 1024;
    size_t zbytes = (o - zoff) * 4;
    int* rowPtr   = (int*)(ws + o); o += (size_t)N + 1;
    int* sSrc     = (int*)(ws + o); o += E;
    int* bOff     = (int*)(ws + o); o += 1025;
    int* bCur     = (int*)(ws + o); o += 1024;
    unsigned int* bucketBuf = (unsigned int*)(ws + o); o += E;

    hipMemsetAsync(ws + zoff, 0, zbytes, stream);

    // ---- CSR build (bucket radix, shared by both layers) ----
    k_bhist<<<256, 256, 0, stream>>>(ei, bSize, E, nB);
    k_bscan<<<1, 512, 0, stream>>>(bSize, bOff, bCur, nB);
    k_part<<<256, 256, 0, stream>>>(ei, bCur, bucketBuf, E, nB);
    k_build<<<nB, 256, 0, stream>>>(bucketBuf, bOff, rowPtr, sSrc, N);

    int gemm_grid = (N + 63) / 64;
    int agg_grid = (N + 15) / 16;

    // ---- layer 1 ----
    k_gemm1<<<gemm_grid, 256, 0, stream>>>(x, W1, att_s1, att_d1, hbuf, as_, ad_, N);
    k_agg<<<agg_grid, 256, 0, stream>>>(rowPtr, sSrc, as_, ad_, hbuf, outb, N);
    k_bnstats<<<512, 256, 0, stream>>>(outb, bnsumA, N);

    // ---- layer 2 (BN1 folded into gemm prologue, bf16 input) ----
    k_gemm2<<<gemm_grid, 256, 0, stream>>>(outb, W2, bnsumA, bn_g1, bn_b1,
            att_s2, att_d2, hbuf, as_, ad_, N);
    k_agg<<<agg_grid, 256, 0, stream>>>(rowPtr, sSrc, as_, ad_, hbuf, outb, N);
    k_bnstats<<<512, 256, 0, stream>>>(outb, bnsumB, N);

    // ---- pool (BN2 folded, bf16 input) + head ----
    k_pool<<<(N + 63) / 64, 128, 0, stream>>>(outb, batch, bnsumB, bn_g2, bn_b2, gsum, gcnt, N);
    k_head<<<1, 256, 0, stream>>>(gsum, gcnt, d1W, d1b, g_d1, b_d1,
                                  d2W, d2b, g_d2, b_d2, fcW, fcb, out);
}